// Round 1
// baseline (87.328 us; speedup 1.0000x reference)
//
#include <hip/hip_runtime.h>

// PosMLP: out[b,q,h,w] = b2 + sum_k relu(rel_y*w1y[k] + rel_x*w1x[k] + b1[k]) * w2[k]
// where [w1y,w1x interleaved | b1 | w2 | b2] = queries[b,q,:] @ w_gen^T + b_gen.
//
// One block per (b,q): 1800 blocks x 256 threads.
//  Phase A: stage query row (C=256 fp32) into LDS, coalesced.
//  Phase B: 65 dot-products, 4 threads per output n (64-float chunks), shfl reduce.
//  Phase C: weights LDS -> registers (broadcast reads).
//  Phase D: 9 pixels/thread at stride 256 -> coalesced output stores; K=16 unrolled.

template<int C, int HD>
__global__ __launch_bounds__(256) void posmlp_kernel(
    const float* __restrict__ queries,  // [BQ, C]
    const float* __restrict__ pos,      // [BQ, 4] = cx, cy, bw, bh
    const float* __restrict__ w_gen,    // [4*HD+1, C]
    const float* __restrict__ b_gen,    // [4*HD+1]
    const int*   __restrict__ Hp,
    const int*   __restrict__ Wp,
    float* __restrict__ out,            // [BQ, H*W]
    int HW)
{
    constexpr int NW = 4 * HD + 1;      // 65
    constexpr int CH = C / 4;           // 64 floats per chunk

    __shared__ __align__(16) float s_q[C];
    __shared__ float s_w[NW + 3];

    const int q = blockIdx.x;
    const int t = threadIdx.x;

    // ---- Phase A: stage query row ----
    for (int c = t; c < C; c += 256) s_q[c] = queries[(size_t)q * C + c];
    __syncthreads();

    // ---- Phase B: generated weights ----
    {
        const int n = t >> 2;           // 0..63
        const int r = t & 3;            // chunk id
        const float4* wg = reinterpret_cast<const float4*>(w_gen + (size_t)n * C + r * CH);
        const float4* sq = reinterpret_cast<const float4*>(s_q + r * CH);
        float acc = 0.f;
        #pragma unroll
        for (int j = 0; j < CH / 4; ++j) {
            float4 a = wg[j], b = sq[j];
            acc = fmaf(a.x, b.x, acc);
            acc = fmaf(a.y, b.y, acc);
            acc = fmaf(a.z, b.z, acc);
            acc = fmaf(a.w, b.w, acc);
        }
        acc += __shfl_xor(acc, 1);
        acc += __shfl_xor(acc, 2);
        if (r == 0) s_w[n] = acc + b_gen[n];

        // n = NW-1 (b2) handled by threads 0..3
        if (t < 4) {
            const float4* wg2 = reinterpret_cast<const float4*>(w_gen + (size_t)(NW - 1) * C + t * CH);
            const float4* sq2 = reinterpret_cast<const float4*>(s_q + t * CH);
            float acc2 = 0.f;
            #pragma unroll
            for (int j = 0; j < CH / 4; ++j) {
                float4 a = wg2[j], b = sq2[j];
                acc2 = fmaf(a.x, b.x, acc2);
                acc2 = fmaf(a.y, b.y, acc2);
                acc2 = fmaf(a.z, b.z, acc2);
                acc2 = fmaf(a.w, b.w, acc2);
            }
            acc2 += __shfl_xor(acc2, 1);
            acc2 += __shfl_xor(acc2, 2);
            if (t == 0) s_w[NW - 1] = acc2 + b_gen[NW - 1];
        }
    }
    __syncthreads();

    // ---- Phase C: weights to registers ----
    float w1y[HD], w1x[HD], b1[HD], w2[HD];
    #pragma unroll
    for (int k = 0; k < HD; ++k) {
        w1y[k] = s_w[2 * k];
        w1x[k] = s_w[2 * k + 1];
        b1[k]  = s_w[2 * HD + k];
        w2[k]  = s_w[3 * HD + k];
    }
    const float b2 = s_w[4 * HD];

    const float cx = pos[(size_t)q * 4 + 0];
    const float cy = pos[(size_t)q * 4 + 1];
    const float inv_bw = 1.f / pos[(size_t)q * 4 + 2];
    const float inv_bh = 1.f / pos[(size_t)q * 4 + 3];

    const int H = Hp[0];
    const int W = Wp[0];
    const float inv_H = 1.f / (float)H;
    const float inv_W = 1.f / (float)W;

    // ---- Phase D: pixels, stride-256 for coalesced stores ----
    int p = t;
    int h = p / W;            // one runtime div per thread
    int w = p - h * W;
    const int dh = 256 / W;
    const int dw = 256 - dh * W;   // < W for W <= 256

    float* outq = out + (size_t)q * HW;
    for (; p < HW; p += 256) {
        const float rel_y = (((float)h + 0.5f) * inv_H - cy) * inv_bh;
        const float rel_x = (((float)w + 0.5f) * inv_W - cx) * inv_bw;
        float acc = b2;
        #pragma unroll
        for (int k = 0; k < HD; ++k) {
            const float hv = fmaf(rel_y, w1y[k], fmaf(rel_x, w1x[k], b1[k]));
            acc = fmaf(fmaxf(hv, 0.f), w2[k], acc);
        }
        outq[p] = acc;
        w += dw;
        h += dh;
        if (w >= W) { w -= W; h += 1; }
    }
}

extern "C" void kernel_launch(void* const* d_in, const int* in_sizes, int n_in,
                              void* d_out, int out_size, void* d_ws, size_t ws_size,
                              hipStream_t stream) {
    const float* queries = (const float*)d_in[0];
    const float* pos     = (const float*)d_in[1];
    const float* w_gen   = (const float*)d_in[2];
    const float* b_gen   = (const float*)d_in[3];
    const int*   Hp      = (const int*)d_in[4];
    const int*   Wp      = (const int*)d_in[5];
    float* out = (float*)d_out;

    const int BQ = in_sizes[1] / 4;        // 1800
    const int HW = out_size / BQ;          // 2304

    // Fixed problem shape: C=256, HD=16 (n_w = 65 = in_sizes[3]).
    posmlp_kernel<256, 16><<<BQ, 256, 0, stream>>>(
        queries, pos, w_gen, b_gen, Hp, Wp, out, HW);
}

// Round 2
// 85.366 us; speedup vs baseline: 1.0230x; 1.0230x over previous
//
#include <hip/hip_runtime.h>

// PosMLP: out[b,q,h,w] = b2 + sum_k relu(rel_y*w1y[k] + rel_x*w1x[k] + b1[k]) * w2[k]
// where [w1y,w1x interleaved | b1 | w2 | b2] = queries[b,q,:] @ w_gen^T + b_gen.
//
// One block per (b,q): 1800 blocks x 256 threads.
//  Phase A: stage query row (C=256 fp32) into LDS, coalesced.
//  Phase B: 65 dot-products, 4 threads per output n (64-float chunks), shfl reduce.
//  Phase C: weights LDS -> registers (broadcast reads).
//  Phase D (templated H,W): fully unrolled — 9 pixels/thread at stride 256,
//    9 independent fma chains inside one unrolled K=16 loop (ILP=9),
//    coalesced nontemporal stores.

template<int C, int HD>
__device__ __forceinline__ void gen_weights(
    const float* __restrict__ queries,
    const float* __restrict__ w_gen,
    const float* __restrict__ b_gen,
    float* s_q, float* s_w, int q, int t)
{
    constexpr int NW = 4 * HD + 1;      // 65
    constexpr int CH = C / 4;           // 64 floats per chunk

    for (int c = t; c < C; c += 256) s_q[c] = queries[(size_t)q * C + c];
    __syncthreads();

    const int n = t >> 2;               // 0..63
    const int r = t & 3;                // chunk id
    const float4* wg = reinterpret_cast<const float4*>(w_gen + (size_t)n * C + r * CH);
    const float4* sq = reinterpret_cast<const float4*>(s_q + r * CH);
    float acc = 0.f;
    #pragma unroll
    for (int j = 0; j < CH / 4; ++j) {
        float4 a = wg[j], b = sq[j];
        acc = fmaf(a.x, b.x, acc);
        acc = fmaf(a.y, b.y, acc);
        acc = fmaf(a.z, b.z, acc);
        acc = fmaf(a.w, b.w, acc);
    }
    acc += __shfl_xor(acc, 1);
    acc += __shfl_xor(acc, 2);
    if (r == 0) s_w[n] = acc + b_gen[n];

    if (t < 4) {                        // row NW-1 (b2)
        const float4* wg2 = reinterpret_cast<const float4*>(w_gen + (size_t)(NW - 1) * C + t * CH);
        const float4* sq2 = reinterpret_cast<const float4*>(s_q + t * CH);
        float acc2 = 0.f;
        #pragma unroll
        for (int j = 0; j < CH / 4; ++j) {
            float4 a = wg2[j], b = sq2[j];
            acc2 = fmaf(a.x, b.x, acc2);
            acc2 = fmaf(a.y, b.y, acc2);
            acc2 = fmaf(a.z, b.z, acc2);
            acc2 = fmaf(a.w, b.w, acc2);
        }
        acc2 += __shfl_xor(acc2, 1);
        acc2 += __shfl_xor(acc2, 2);
        if (t == 0) s_w[NW - 1] = acc2 + b_gen[NW - 1];
    }
    __syncthreads();
}

// Specialized: H, W compile-time -> full unroll of the pixel loop.
template<int C, int HD, int H, int W>
__global__ __launch_bounds__(256) void posmlp_kernel_hw(
    const float* __restrict__ queries,
    const float* __restrict__ pos,
    const float* __restrict__ w_gen,
    const float* __restrict__ b_gen,
    float* __restrict__ out)
{
    constexpr int NW  = 4 * HD + 1;
    constexpr int HW  = H * W;
    constexpr int PPT = (HW + 255) / 256;   // pixels per thread (48x48 -> 9, exact)
    static_assert(HW % 256 == 0, "HW must be divisible by 256 for this path");

    __shared__ __align__(16) float s_q[C];
    __shared__ float s_w[NW + 3];

    const int q = blockIdx.x;
    const int t = threadIdx.x;

    gen_weights<C, HD>(queries, w_gen, b_gen, s_q, s_w, q, t);

    // weights -> registers
    float w1y[HD], w1x[HD], b1[HD], w2[HD];
    #pragma unroll
    for (int k = 0; k < HD; ++k) {
        w1y[k] = s_w[2 * k];
        w1x[k] = s_w[2 * k + 1];
        b1[k]  = s_w[2 * HD + k];
        w2[k]  = s_w[3 * HD + k];
    }
    const float b2 = s_w[4 * HD];

    const float cx = pos[(size_t)q * 4 + 0];
    const float cy = pos[(size_t)q * 4 + 1];
    const float inv_bw = 1.f / pos[(size_t)q * 4 + 2];
    const float inv_bh = 1.f / pos[(size_t)q * 4 + 3];
    constexpr float inv_H = 1.f / (float)H;
    constexpr float inv_W = 1.f / (float)W;

    // precompute all PPT (rel_x, rel_y); W constexpr -> divisions strength-reduced
    float relx[PPT], rely[PPT];
    {
        int h = t / W;
        int w = t - h * W;
        constexpr int DH = 256 / W;          // 5
        constexpr int DW = 256 - DH * W;     // 16
        #pragma unroll
        for (int i = 0; i < PPT; ++i) {
            rely[i] = (((float)h + 0.5f) * inv_H - cy) * inv_bh;
            relx[i] = (((float)w + 0.5f) * inv_W - cx) * inv_bw;
            w += DW; h += DH;
            if (w >= W) { w -= W; h += 1; }
        }
    }

    float acc[PPT];
    #pragma unroll
    for (int i = 0; i < PPT; ++i) acc[i] = b2;

    #pragma unroll
    for (int k = 0; k < HD; ++k) {
        const float ay = w1y[k], ax = w1x[k], ab = b1[k], aw = w2[k];
        #pragma unroll
        for (int i = 0; i < PPT; ++i) {
            const float hv = fmaf(rely[i], ay, fmaf(relx[i], ax, ab));
            acc[i] = fmaf(fmaxf(hv, 0.f), aw, acc[i]);
        }
    }

    float* outq = out + (size_t)q * HW + t;
    #pragma unroll
    for (int i = 0; i < PPT; ++i)
        __builtin_nontemporal_store(acc[i], outq + i * 256);
}

// Generic fallback (runtime H, W read from device arrays).
template<int C, int HD>
__global__ __launch_bounds__(256) void posmlp_kernel_gen(
    const float* __restrict__ queries,
    const float* __restrict__ pos,
    const float* __restrict__ w_gen,
    const float* __restrict__ b_gen,
    const int* __restrict__ Hp, const int* __restrict__ Wp,
    float* __restrict__ out, int HW)
{
    constexpr int NW = 4 * HD + 1;
    __shared__ __align__(16) float s_q[C];
    __shared__ float s_w[NW + 3];

    const int q = blockIdx.x;
    const int t = threadIdx.x;

    gen_weights<C, HD>(queries, w_gen, b_gen, s_q, s_w, q, t);

    float w1y[HD], w1x[HD], b1[HD], w2[HD];
    #pragma unroll
    for (int k = 0; k < HD; ++k) {
        w1y[k] = s_w[2 * k];
        w1x[k] = s_w[2 * k + 1];
        b1[k]  = s_w[2 * HD + k];
        w2[k]  = s_w[3 * HD + k];
    }
    const float b2 = s_w[4 * HD];

    const float cx = pos[(size_t)q * 4 + 0];
    const float cy = pos[(size_t)q * 4 + 1];
    const float inv_bw = 1.f / pos[(size_t)q * 4 + 2];
    const float inv_bh = 1.f / pos[(size_t)q * 4 + 3];
    const int H = Hp[0], W = Wp[0];
    const float inv_H = 1.f / (float)H;
    const float inv_W = 1.f / (float)W;

    float* outq = out + (size_t)q * HW;
    for (int p = t; p < HW; p += 256) {
        const int h = p / W;
        const int w = p - h * W;
        const float rel_y = (((float)h + 0.5f) * inv_H - cy) * inv_bh;
        const float rel_x = (((float)w + 0.5f) * inv_W - cx) * inv_bw;
        float a = b2;
        #pragma unroll
        for (int k = 0; k < HD; ++k) {
            const float hv = fmaf(rel_y, w1y[k], fmaf(rel_x, w1x[k], b1[k]));
            a = fmaf(fmaxf(hv, 0.f), w2[k], a);
        }
        outq[p] = a;
    }
}

extern "C" void kernel_launch(void* const* d_in, const int* in_sizes, int n_in,
                              void* d_out, int out_size, void* d_ws, size_t ws_size,
                              hipStream_t stream) {
    const float* queries = (const float*)d_in[0];
    const float* pos     = (const float*)d_in[1];
    const float* w_gen   = (const float*)d_in[2];
    const float* b_gen   = (const float*)d_in[3];
    const int*   Hp      = (const int*)d_in[4];
    const int*   Wp      = (const int*)d_in[5];
    float* out = (float*)d_out;

    const int BQ = in_sizes[1] / 4;        // 1800
    const int HW = out_size / BQ;          // 2304

    if (HW == 48 * 48) {
        posmlp_kernel_hw<256, 16, 48, 48><<<BQ, 256, 0, stream>>>(
            queries, pos, w_gen, b_gen, out);
    } else {
        posmlp_kernel_gen<256, 16><<<BQ, 256, 0, stream>>>(
            queries, pos, w_gen, b_gen, Hp, Wp, out, HW);
    }
}